// Round 2
// baseline (6703.946 us; speedup 1.0000x reference)
//
#include <hip/hip_runtime.h>
#include <hip/hip_bf16.h>
#include <math.h>

#define N_NODES  100000
#define N_EDGES  1600000
#define N_GRAPHS 1024

typedef __hip_bfloat16 bf16;

__device__ __forceinline__ float b2f(bf16 v) { return __bfloat162float(v); }

// ---------------- dtype sniff: flag=1 if external float tensors are bf16 ----
__global__ void sniff_dtype(const unsigned short* __restrict__ p, int* __restrict__ flag) {
    if (blockIdx.x == 0 && threadIdx.x == 0) {
        int bad = 0;
        for (int i = 0; i < 256; ++i) {
            unsigned int ui = ((unsigned int)p[i]) << 16;
            float f = __uint_as_float(ui);
            if (!(fabsf(f) < 100.f)) bad++;   // counts huge values and NaNs
        }
        *flag = (bad == 0) ? 1 : 0;
    }
}

// ---------------- convert external float tensor -> fp32 ws ----------------
__global__ void cvt_f(const void* __restrict__ src, float* __restrict__ dst,
                      int n, const int* __restrict__ flag) {
    int i = blockIdx.x * blockDim.x + threadIdx.x;
    if (i >= n) return;
    if (*flag) dst[i] = b2f(((const bf16*)src)[i]);
    else       dst[i] = ((const float*)src)[i];
}

// ---------------- degree / norm ----------------
__global__ void deg_init(int* degi) {
    int i = blockIdx.x * blockDim.x + threadIdx.x;
    if (i < N_NODES) degi[i] = 2;   // two self-loop copies per node
}

__global__ void deg_edges(const int* __restrict__ dst, int* __restrict__ degi) {
    int e = blockIdx.x * blockDim.x + threadIdx.x;
    if (e < N_EDGES) atomicAdd(&degi[dst[e]], 1);
}

__global__ void dinv_k(const int* __restrict__ degi, float* __restrict__ dinv) {
    int i = blockIdx.x * blockDim.x + threadIdx.x;
    if (i < N_NODES) dinv[i] = rsqrtf((float)degi[i]);
}

// ---------------- GEMM: H[M x 128] = X[M x K] @ W[K x 128] ----------------
// block = 256 threads -> 16 rows x 128 cols. Each thread: 4 rows x 2 adjacent cols.
// XMODE 0: X is fp32 ws buffer. XMODE 1: X is external (dtype per *flagp).
template<int K, int XMODE>
__global__ __launch_bounds__(256) void gemm_n128(const void* __restrict__ Xv,
        const float* __restrict__ W, float* __restrict__ H, int M,
        const int* __restrict__ flagp)
{
    __shared__ float Xs[16][K];
    int tid = threadIdx.x;
    int rowBase = blockIdx.x * 16;
    const int isb = XMODE ? *flagp : 0;
    for (int e = tid; e < 16 * K; e += 256) {
        int r = e / K, cc = e % K;
        int gr = rowBase + r;
        float v = 0.f;
        if (gr < M) {
            size_t off = (size_t)gr * K + cc;
            if (XMODE)
                v = isb ? b2f(((const bf16*)Xv)[off]) : ((const float*)Xv)[off];
            else
                v = ((const float*)Xv)[off];
        }
        Xs[r][cc] = v;
    }
    __syncthreads();

    int c  = tid & 63;   // col pair: cols 2c, 2c+1
    int rg = tid >> 6;   // rows rg*4 .. rg*4+3
    float acc0[4], acc1[4];
#pragma unroll
    for (int j = 0; j < 4; ++j) { acc0[j] = 0.f; acc1[j] = 0.f; }

    for (int k = 0; k < K; k += 2) {
        float2 w0 = *(const float2*)(W + (size_t)k * 128 + 2 * c);
        float2 w1 = *(const float2*)(W + (size_t)(k + 1) * 128 + 2 * c);
#pragma unroll
        for (int j = 0; j < 4; ++j) {
            float2 x2 = *(const float2*)&Xs[rg * 4 + j][k];
            acc0[j] += x2.x * w0.x + x2.y * w1.x;
            acc1[j] += x2.x * w0.y + x2.y * w1.y;
        }
    }
#pragma unroll
    for (int j = 0; j < 4; ++j) {
        int gr = rowBase + rg * 4 + j;
        if (gr < M)
            *(float2*)(H + (size_t)gr * 128 + 2 * c) = make_float2(acc0[j], acc1[j]);
    }
}

// ---------------- A = (2*dinv^2) * H + bias  (self-loops + bias) ----------------
__global__ void init_agg(const float* __restrict__ H, const float* __restrict__ dinv,
                         const float* __restrict__ bias, float* __restrict__ A)
{
    int idx = blockIdx.x * blockDim.x + threadIdx.x;  // over N_NODES*32 float4 groups
    if (idx >= N_NODES * 32) return;
    int node = idx >> 5;
    int f = (idx & 31) * 4;
    float s = dinv[node]; s = 2.f * s * s;
    float4 h = ((const float4*)H)[idx];
    float4 bb = *(const float4*)(bias + f);
    float4 o;
    o.x = s * h.x + bb.x;
    o.y = s * h.y + bb.y;
    o.z = s * h.z + bb.z;
    o.w = s * h.w + bb.w;
    ((float4*)A)[idx] = o;
}

// ---------------- edge scatter: A[dst] += norm * H[src] ----------------
// one wave (64 lanes) per edge, 2 floats per lane
__global__ __launch_bounds__(256) void scatter_edges(const int* __restrict__ src,
        const int* __restrict__ dst, const float* __restrict__ dinv,
        const float* __restrict__ H, float* __restrict__ A)
{
    long long tid = (long long)blockIdx.x * 256 + threadIdx.x;
    int edge = (int)(tid >> 6);
    int lane = (int)(tid & 63);
    if (edge >= N_EDGES) return;
    int s = src[edge], d = dst[edge];
    float nrm = dinv[s] * dinv[d];
    float2 v = ((const float2*)(H + (size_t)s * 128))[lane];
    float* out = A + (size_t)d * 128 + lane * 2;
    atomicAdd(out,     v.x * nrm);
    atomicAdd(out + 1, v.y * nrm);
}

// ---------------- relu in place ----------------
__global__ void relu_k(float* __restrict__ A, int n4) {
    int i = blockIdx.x * blockDim.x + threadIdx.x;
    if (i >= n4) return;
    float4 v = ((float4*)A)[i];
    v.x = fmaxf(v.x, 0.f); v.y = fmaxf(v.y, 0.f);
    v.z = fmaxf(v.z, 0.f); v.w = fmaxf(v.w, 0.f);
    ((float4*)A)[i] = v;
}

// ---------------- per-graph mean/max pooling (batch is sorted) ----------------
__global__ __launch_bounds__(128) void pool_k(const float* __restrict__ A,
        const int* __restrict__ batch, float* __restrict__ concat)
{
    __shared__ int sb[2];
    int g = blockIdx.x;
    if (threadIdx.x == 0) {
        int lo = 0, hi = N_NODES;
        while (lo < hi) { int m = (lo + hi) >> 1; if (batch[m] < g) lo = m + 1; else hi = m; }
        sb[0] = lo;
        hi = N_NODES;
        while (lo < hi) { int m = (lo + hi) >> 1; if (batch[m] < g + 1) lo = m + 1; else hi = m; }
        sb[1] = lo;
    }
    __syncthreads();
    int start = sb[0], end = sb[1];
    int t = threadIdx.x;
    float sum = 0.f, mx = -3.4e38f;
    for (int n = start; n < end; ++n) {
        float v = A[(size_t)n * 128 + t];
        sum += v; mx = fmaxf(mx, v);
    }
    int cnt = end - start;
    float mean = sum / (float)(cnt > 0 ? cnt : 1);
    if (cnt == 0) mx = 0.f;
    concat[g * 384 + t] = mean;
    concat[g * 384 + 128 + t] = mx;
}

// ---------------- small row GEMM: out[g][col] = relu(X[g,:] @ W + bias) ----------------
// block g, blockDim = N (output cols), W is [KD x N] row-major fp32
template<int KD, bool EXT>
__global__ void rowmm(const void* __restrict__ Xv, int ldx,
                      const float* __restrict__ W, const float* __restrict__ bias,
                      float* __restrict__ out, int ldo, const int* __restrict__ flagp)
{
    extern __shared__ float xs[];
    int g = blockIdx.x;
    int col = threadIdx.x;
    int N = blockDim.x;
    const int isb = EXT ? *flagp : 0;
    for (int k = col; k < KD; k += N) {
        size_t off = (size_t)g * ldx + k;
        xs[k] = EXT ? (isb ? b2f(((const bf16*)Xv)[off]) : ((const float*)Xv)[off])
                    : ((const float*)Xv)[off];
    }
    __syncthreads();
    float acc = bias[col];
    for (int k = 0; k < KD; ++k)
        acc += xs[k] * W[(size_t)k * N + col];
    out[(size_t)g * ldo + col] = fmaxf(acc, 0.f);
}

// ---------------- final dot + sigmoid ----------------
__global__ __launch_bounds__(256) void head3(const float* __restrict__ u2,
        const float* __restrict__ Wf3, const float* __restrict__ bf3,
        void* __restrict__ out, const int* __restrict__ flagp)
{
    int g = blockIdx.x * 4 + (threadIdx.x >> 6);
    int lane = threadIdx.x & 63;
    float2 v = ((const float2*)(u2 + (size_t)g * 128))[lane];
    float2 w = ((const float2*)Wf3)[lane];
    float acc = v.x * w.x + v.y * w.y;
    for (int off = 32; off > 0; off >>= 1) acc += __shfl_down(acc, off);
    if (lane == 0) {
        float z = acc + bf3[0];
        float sg = 1.f / (1.f + expf(-z));
        if (*flagp) ((bf16*)out)[g] = __float2bfloat16(sg);
        else        ((float*)out)[g] = sg;
    }
}

extern "C" void kernel_launch(void* const* d_in, const int* in_sizes, int n_in,
                              void* d_out, int out_size, void* d_ws, size_t ws_size,
                              hipStream_t stream) {
    const void* x_graph    = d_in[0];
    const int*  edge_index = (const int*)d_in[1];
    const int*  batch      = (const int*)d_in[2];
    const void* x_tab      = d_in[3];

    const int* src  = edge_index;
    const int* dstp = edge_index + N_EDGES;

    // ---------------- workspace layout (fp32 elements) ----------------
    float* base = (float*)d_ws;
    int*   flag = (int*)base;                         // [0]: dtype flag (16B slot)
    float* A    = base + 4;                           // 100000*128 fp32
    float* B    = A + (size_t)N_NODES * 128;          // 100000*128 fp32
    float* wb   = B + (size_t)N_NODES * 128;          // converted weights (fp32)
    float* p = wb;
    float* Wg1f = p; p += 64 * 128;  float* bg1f = p; p += 128;
    float* Wg2f = p; p += 128 * 128; float* bg2f = p; p += 128;
    float* Wg3f = p; p += 128 * 128; float* bg3f = p; p += 128;
    float* Wg4f = p; p += 128 * 128; float* bg4f = p; p += 128;
    float* Wt1f = p; p += 200 * 256; float* bt1f = p; p += 256;
    float* Wt2f = p; p += 256 * 128; float* bt2f = p; p += 128;
    float* Wf1f = p; p += 384 * 256; float* bf1f = p; p += 256;
    float* Wf2f = p; p += 256 * 128; float* bf2f = p; p += 128;
    float* Wf3f = p; p += 128;       float* bf3f = p; p += 1;
    int*   degi = (int*)(p + 3);                      // align up a bit
    float* dinv = (float*)(degi + N_NODES);
    float* concat = dinv + N_NODES;                   // 1024*384
    float* t1   = concat + N_GRAPHS * 384;            // 1024*256
    float* u1   = t1 + N_GRAPHS * 256;                // 1024*256
    float* u2   = u1 + N_GRAPHS * 256;                // 1024*128

    // ---------------- dtype sniff + weight conversion ----------------
    sniff_dtype<<<1, 64, 0, stream>>>((const unsigned short*)x_graph, flag);
    const float* Wfp[9] = {Wg1f, Wg2f, Wg3f, Wg4f, Wt1f, Wt2f, Wf1f, Wf2f, Wf3f};
    const float* bfp[9] = {bg1f, bg2f, bg3f, bg4f, bt1f, bt2f, bf1f, bf2f, bf3f};
    const int    wsz[9] = {64*128, 128*128, 128*128, 128*128, 200*256, 256*128,
                           384*256, 256*128, 128};
    const int    bsz[9] = {128, 128, 128, 128, 256, 128, 256, 128, 1};
    for (int i = 0; i < 9; ++i) {
        cvt_f<<<(wsz[i] + 255) / 256, 256, 0, stream>>>(d_in[4 + 2*i], (float*)Wfp[i], wsz[i], flag);
        cvt_f<<<(bsz[i] + 255) / 256, 256, 0, stream>>>(d_in[5 + 2*i], (float*)bfp[i], bsz[i], flag);
    }

    // degree / norm
    deg_init<<<(N_NODES + 255) / 256, 256, 0, stream>>>(degi);
    deg_edges<<<(N_EDGES + 255) / 256, 256, 0, stream>>>(dstp, degi);
    dinv_k<<<(N_NODES + 255) / 256, 256, 0, stream>>>(degi, dinv);

    const int gemmGrid = (N_NODES + 15) / 16;            // 6250
    const int eaGrid   = (N_NODES * 32 + 255) / 256;     // elementwise over nodes*128/4
    const int scGrid   = N_EDGES / 4;                    // edges*64/256

    const float* WgL[4] = {Wg1f, Wg2f, Wg3f, Wg4f};
    const float* bgL[4] = {bg1f, bg2f, bg3f, bg4f};

    // 4 GCN layers; ping-pong A (features) / B (XW)
    for (int l = 0; l < 4; ++l) {
        if (l == 0)
            gemm_n128<64, 1><<<gemmGrid, 256, 0, stream>>>(x_graph, WgL[0], B, N_NODES, flag);
        else
            gemm_n128<128, 0><<<gemmGrid, 256, 0, stream>>>(A, WgL[l], B, N_NODES, flag);
        init_agg<<<eaGrid, 256, 0, stream>>>(B, dinv, bgL[l], A);
        scatter_edges<<<scGrid, 256, 0, stream>>>(src, dstp, dinv, B, A);
        relu_k<<<eaGrid, 256, 0, stream>>>(A, N_NODES * 32);
    }

    // pooling -> concat[:, 0:256]
    pool_k<<<N_GRAPHS, 128, 0, stream>>>(A, batch, concat);

    // tabular branch -> concat[:, 256:384]
    rowmm<200, true><<<N_GRAPHS, 256, 200 * 4, stream>>>(x_tab, 200, Wt1f, bt1f, t1, 256, flag);
    rowmm<256, false><<<N_GRAPHS, 128, 256 * 4, stream>>>(t1, 256, Wt2f, bt2f, concat + 256, 384, flag);

    // fused head
    rowmm<384, false><<<N_GRAPHS, 256, 384 * 4, stream>>>(concat, 384, Wf1f, bf1f, u1, 256, flag);
    rowmm<256, false><<<N_GRAPHS, 128, 256 * 4, stream>>>(u1, 256, Wf2f, bf2f, u2, 128, flag);
    head3<<<N_GRAPHS / 4, 256, 0, stream>>>(u2, Wf3f, bf3f, d_out, flag);
}

// Round 3
// 1443.690 us; speedup vs baseline: 4.6436x; 4.6436x over previous
//
#include <hip/hip_runtime.h>
#include <hip/hip_bf16.h>
#include <math.h>

#define N_NODES  100000
#define N_EDGES  1600000
#define N_GRAPHS 1024

typedef __hip_bfloat16 bf16;

__device__ __forceinline__ float b2f(bf16 v) { return __bfloat162float(v); }

// ---------------- dtype sniff: flag=1 if external float tensors are bf16 ----
__global__ void sniff_dtype(const unsigned short* __restrict__ p, int* __restrict__ flag) {
    if (blockIdx.x == 0 && threadIdx.x == 0) {
        int bad = 0;
        for (int i = 0; i < 256; ++i) {
            unsigned int ui = ((unsigned int)p[i]) << 16;
            float f = __uint_as_float(ui);
            if (!(fabsf(f) < 100.f)) bad++;   // counts huge values and NaNs
        }
        *flag = (bad == 0) ? 1 : 0;
    }
}

// ---------------- convert external float tensor -> fp32 ws ----------------
__global__ void cvt_f(const void* __restrict__ src, float* __restrict__ dst,
                      int n, const int* __restrict__ flag) {
    int i = blockIdx.x * blockDim.x + threadIdx.x;
    if (i >= n) return;
    if (*flag) dst[i] = b2f(((const bf16*)src)[i]);
    else       dst[i] = ((const float*)src)[i];
}

// ---------------- degree / norm ----------------
__global__ void deg_init(int* degi) {
    int i = blockIdx.x * blockDim.x + threadIdx.x;
    if (i < N_NODES) degi[i] = 2;   // two self-loop copies per node
}

__global__ void deg_edges(const int* __restrict__ dst, int* __restrict__ degi) {
    int e = blockIdx.x * blockDim.x + threadIdx.x;
    if (e < N_EDGES) atomicAdd(&degi[dst[e]], 1);
}

__global__ void dinv_k(const int* __restrict__ degi, float* __restrict__ dinv) {
    int i = blockIdx.x * blockDim.x + threadIdx.x;
    if (i < N_NODES) dinv[i] = rsqrtf((float)degi[i]);
}

// ---------------- CSR build: prefix-sum of edge-degree, then slot fill ----
#define SCAN_B 256
// per-block exclusive scan of (degi-2); block totals to bsum
__global__ void scan1(const int* __restrict__ degi, int* __restrict__ ex,
                      int* __restrict__ bsum) {
    __shared__ int s[SCAN_B];
    int i = blockIdx.x * SCAN_B + threadIdx.x;
    int v = (i < N_NODES) ? (degi[i] - 2) : 0;
    s[threadIdx.x] = v;
    __syncthreads();
    for (int off = 1; off < SCAN_B; off <<= 1) {
        int t = (threadIdx.x >= off) ? s[threadIdx.x - off] : 0;
        __syncthreads();
        if (threadIdx.x >= off) s[threadIdx.x] += t;
        __syncthreads();
    }
    if (i < N_NODES) ex[i] = s[threadIdx.x] - v;   // exclusive within block
    if (threadIdx.x == SCAN_B - 1) bsum[blockIdx.x] = s[SCAN_B - 1];
}

// serial exclusive scan of block sums (391 elements, one-time)
__global__ void scan2(int* __restrict__ bsum, int nb) {
    if (blockIdx.x == 0 && threadIdx.x == 0) {
        int acc = 0;
        for (int i = 0; i < nb; ++i) { int t = bsum[i]; bsum[i] = acc; acc += t; }
    }
}

// rowptr[i] = ex[i] + bsum[block]; zero the fill counters
__global__ void scan3(int* __restrict__ rowptr, const int* __restrict__ bsum,
                      int* __restrict__ cnt) {
    int i = blockIdx.x * SCAN_B + threadIdx.x;
    if (i >= N_NODES) return;
    rowptr[i] += bsum[blockIdx.x];
    cnt[i] = 0;
}

__global__ void fill_csr(const int* __restrict__ src, const int* __restrict__ dst,
                         const float* __restrict__ dinv, const int* __restrict__ rowptr,
                         int* __restrict__ cnt, int* __restrict__ csr_src,
                         float* __restrict__ csr_w) {
    int e = blockIdx.x * 256 + threadIdx.x;
    if (e >= N_EDGES) return;
    int s = src[e], d = dst[e];
    int pos = rowptr[d] + atomicAdd(&cnt[d], 1);
    csr_src[pos] = s;
    csr_w[pos] = dinv[s] * dinv[d];
}

// ---------------- GEMM: H[M x 128] = X[M x K] @ W[K x 128] ----------------
template<int K, int XMODE>
__global__ __launch_bounds__(256) void gemm_n128(const void* __restrict__ Xv,
        const float* __restrict__ W, float* __restrict__ H, int M,
        const int* __restrict__ flagp)
{
    __shared__ float Xs[16][K];
    int tid = threadIdx.x;
    int rowBase = blockIdx.x * 16;
    const int isb = XMODE ? *flagp : 0;
    for (int e = tid; e < 16 * K; e += 256) {
        int r = e / K, cc = e % K;
        int gr = rowBase + r;
        float v = 0.f;
        if (gr < M) {
            size_t off = (size_t)gr * K + cc;
            if (XMODE)
                v = isb ? b2f(((const bf16*)Xv)[off]) : ((const float*)Xv)[off];
            else
                v = ((const float*)Xv)[off];
        }
        Xs[r][cc] = v;
    }
    __syncthreads();

    int c  = tid & 63;
    int rg = tid >> 6;
    float acc0[4], acc1[4];
#pragma unroll
    for (int j = 0; j < 4; ++j) { acc0[j] = 0.f; acc1[j] = 0.f; }

    for (int k = 0; k < K; k += 2) {
        float2 w0 = *(const float2*)(W + (size_t)k * 128 + 2 * c);
        float2 w1 = *(const float2*)(W + (size_t)(k + 1) * 128 + 2 * c);
#pragma unroll
        for (int j = 0; j < 4; ++j) {
            float2 x2 = *(const float2*)&Xs[rg * 4 + j][k];
            acc0[j] += x2.x * w0.x + x2.y * w1.x;
            acc1[j] += x2.x * w0.y + x2.y * w1.y;
        }
    }
#pragma unroll
    for (int j = 0; j < 4; ++j) {
        int gr = rowBase + rg * 4 + j;
        if (gr < M)
            *(float2*)(H + (size_t)gr * 128 + 2 * c) = make_float2(acc0[j], acc1[j]);
    }
}

// ---------------- fused aggregate: A[n] = relu(bias + 2*dinv^2*H[n] + sum_e w_e*H[src_e]) ----
// one wave per node, 2 floats per lane
__global__ __launch_bounds__(256) void gather_agg(
        const int* __restrict__ rowptr, const int* __restrict__ degi,
        const int* __restrict__ csr_src, const float* __restrict__ csr_w,
        const float* __restrict__ H, const float* __restrict__ dinv,
        const float* __restrict__ bias, float* __restrict__ A)
{
    int node = blockIdx.x * 4 + (threadIdx.x >> 6);
    if (node >= N_NODES) return;
    int lane = threadIdx.x & 63;
    const float2* H2 = (const float2*)H;
    float2 bb = ((const float2*)bias)[lane];
    float dv = dinv[node];
    float selfw = 2.f * dv * dv;
    float2 h0 = H2[(size_t)node * 64 + lane];
    float accx = bb.x + selfw * h0.x;
    float accy = bb.y + selfw * h0.y;
    int p = rowptr[node];
    int end = p + (degi[node] - 2);
    for (; p + 4 <= end; p += 4) {
        int s0 = csr_src[p],   s1 = csr_src[p+1];
        int s2 = csr_src[p+2], s3 = csr_src[p+3];
        float w0 = csr_w[p],   w1 = csr_w[p+1];
        float w2 = csr_w[p+2], w3 = csr_w[p+3];
        float2 v0 = H2[(size_t)s0 * 64 + lane];
        float2 v1 = H2[(size_t)s1 * 64 + lane];
        float2 v2 = H2[(size_t)s2 * 64 + lane];
        float2 v3 = H2[(size_t)s3 * 64 + lane];
        accx += w0 * v0.x + w1 * v1.x + w2 * v2.x + w3 * v3.x;
        accy += w0 * v0.y + w1 * v1.y + w2 * v2.y + w3 * v3.y;
    }
    for (; p < end; ++p) {
        int s = csr_src[p]; float w = csr_w[p];
        float2 v = H2[(size_t)s * 64 + lane];
        accx += w * v.x; accy += w * v.y;
    }
    accx = fmaxf(accx, 0.f);
    accy = fmaxf(accy, 0.f);
    ((float2*)A)[(size_t)node * 64 + lane] = make_float2(accx, accy);
}

// ---------------- per-graph mean/max pooling (batch is sorted) ----------------
__global__ __launch_bounds__(128) void pool_k(const float* __restrict__ A,
        const int* __restrict__ batch, float* __restrict__ concat)
{
    __shared__ int sb[2];
    int g = blockIdx.x;
    if (threadIdx.x == 0) {
        int lo = 0, hi = N_NODES;
        while (lo < hi) { int m = (lo + hi) >> 1; if (batch[m] < g) lo = m + 1; else hi = m; }
        sb[0] = lo;
        hi = N_NODES;
        while (lo < hi) { int m = (lo + hi) >> 1; if (batch[m] < g + 1) lo = m + 1; else hi = m; }
        sb[1] = lo;
    }
    __syncthreads();
    int start = sb[0], end = sb[1];
    int t = threadIdx.x;
    float sum = 0.f, mx = -3.4e38f;
    for (int n = start; n < end; ++n) {
        float v = A[(size_t)n * 128 + t];
        sum += v; mx = fmaxf(mx, v);
    }
    int cnt = end - start;
    float mean = sum / (float)(cnt > 0 ? cnt : 1);
    if (cnt == 0) mx = 0.f;
    concat[g * 384 + t] = mean;
    concat[g * 384 + 128 + t] = mx;
}

// ---------------- small row GEMM ----------------
template<int KD, bool EXT>
__global__ void rowmm(const void* __restrict__ Xv, int ldx,
                      const float* __restrict__ W, const float* __restrict__ bias,
                      float* __restrict__ out, int ldo, const int* __restrict__ flagp)
{
    extern __shared__ float xs[];
    int g = blockIdx.x;
    int col = threadIdx.x;
    int N = blockDim.x;
    const int isb = EXT ? *flagp : 0;
    for (int k = col; k < KD; k += N) {
        size_t off = (size_t)g * ldx + k;
        xs[k] = EXT ? (isb ? b2f(((const bf16*)Xv)[off]) : ((const float*)Xv)[off])
                    : ((const float*)Xv)[off];
    }
    __syncthreads();
    float acc = bias[col];
    for (int k = 0; k < KD; ++k)
        acc += xs[k] * W[(size_t)k * N + col];
    out[(size_t)g * ldo + col] = fmaxf(acc, 0.f);
}

// ---------------- final dot + sigmoid ----------------
__global__ __launch_bounds__(256) void head3(const float* __restrict__ u2,
        const float* __restrict__ Wf3, const float* __restrict__ bf3,
        void* __restrict__ out, const int* __restrict__ flagp)
{
    int g = blockIdx.x * 4 + (threadIdx.x >> 6);
    int lane = threadIdx.x & 63;
    float2 v = ((const float2*)(u2 + (size_t)g * 128))[lane];
    float2 w = ((const float2*)Wf3)[lane];
    float acc = v.x * w.x + v.y * w.y;
    for (int off = 32; off > 0; off >>= 1) acc += __shfl_down(acc, off);
    if (lane == 0) {
        float z = acc + bf3[0];
        float sg = 1.f / (1.f + expf(-z));
        if (*flagp) ((bf16*)out)[g] = __float2bfloat16(sg);
        else        ((float*)out)[g] = sg;
    }
}

extern "C" void kernel_launch(void* const* d_in, const int* in_sizes, int n_in,
                              void* d_out, int out_size, void* d_ws, size_t ws_size,
                              hipStream_t stream) {
    const void* x_graph    = d_in[0];
    const int*  edge_index = (const int*)d_in[1];
    const int*  batch      = (const int*)d_in[2];
    const void* x_tab      = d_in[3];

    const int* src  = edge_index;
    const int* dstp = edge_index + N_EDGES;

    // ---------------- workspace layout (fp32 elements) ----------------
    float* base = (float*)d_ws;
    int*   flag = (int*)base;                         // [0]: dtype flag (16B slot)
    float* A    = base + 4;                           // 100000*128 fp32
    float* B    = A + (size_t)N_NODES * 128;          // 100000*128 fp32
    float* p    = B + (size_t)N_NODES * 128;
    float* Wg1f = p; p += 64 * 128;  float* bg1f = p; p += 128;
    float* Wg2f = p; p += 128 * 128; float* bg2f = p; p += 128;
    float* Wg3f = p; p += 128 * 128; float* bg3f = p; p += 128;
    float* Wg4f = p; p += 128 * 128; float* bg4f = p; p += 128;
    float* Wt1f = p; p += 200 * 256; float* bt1f = p; p += 256;
    float* Wt2f = p; p += 256 * 128; float* bt2f = p; p += 128;
    float* Wf1f = p; p += 384 * 256; float* bf1f = p; p += 256;
    float* Wf2f = p; p += 256 * 128; float* bf2f = p; p += 128;
    float* Wf3f = p; p += 128;       float* bf3f = p; p += 4;
    int*   degi   = (int*)p;            p += N_NODES;
    float* dinv   = p;                  p += N_NODES;
    int*   rowptr = (int*)p;            p += N_NODES;
    int*   cnt    = (int*)p;            p += N_NODES;
    int*   bsum   = (int*)p;            p += 512;
    int*   csr_src= (int*)p;            p += N_EDGES;
    float* csr_w  = p;                  p += N_EDGES;
    float* concat = p;                  p += N_GRAPHS * 384;
    float* t1     = p;                  p += N_GRAPHS * 256;
    float* u1     = p;                  p += N_GRAPHS * 256;
    float* u2     = p;                  p += N_GRAPHS * 128;

    // ---------------- dtype sniff + weight conversion ----------------
    sniff_dtype<<<1, 64, 0, stream>>>((const unsigned short*)x_graph, flag);
    const float* Wfp[9] = {Wg1f, Wg2f, Wg3f, Wg4f, Wt1f, Wt2f, Wf1f, Wf2f, Wf3f};
    const float* bfp[9] = {bg1f, bg2f, bg3f, bg4f, bt1f, bt2f, bf1f, bf2f, bf3f};
    const int    wsz[9] = {64*128, 128*128, 128*128, 128*128, 200*256, 256*128,
                           384*256, 256*128, 128};
    const int    bsz[9] = {128, 128, 128, 128, 256, 128, 256, 128, 1};
    for (int i = 0; i < 9; ++i) {
        cvt_f<<<(wsz[i] + 255) / 256, 256, 0, stream>>>(d_in[4 + 2*i], (float*)Wfp[i], wsz[i], flag);
        cvt_f<<<(bsz[i] + 255) / 256, 256, 0, stream>>>(d_in[5 + 2*i], (float*)bfp[i], bsz[i], flag);
    }

    // ---------------- degree / norm / CSR ----------------
    const int nb = (N_NODES + SCAN_B - 1) / SCAN_B;   // 391
    deg_init<<<(N_NODES + 255) / 256, 256, 0, stream>>>(degi);
    deg_edges<<<(N_EDGES + 255) / 256, 256, 0, stream>>>(dstp, degi);
    dinv_k<<<(N_NODES + 255) / 256, 256, 0, stream>>>(degi, dinv);
    scan1<<<nb, SCAN_B, 0, stream>>>(degi, rowptr, bsum);
    scan2<<<1, 64, 0, stream>>>(bsum, nb);
    scan3<<<nb, SCAN_B, 0, stream>>>(rowptr, bsum, cnt);
    fill_csr<<<(N_EDGES + 255) / 256, 256, 0, stream>>>(src, dstp, dinv, rowptr, cnt,
                                                        csr_src, csr_w);

    const int gemmGrid = (N_NODES + 15) / 16;   // 6250
    const int aggGrid  = (N_NODES + 3) / 4;     // 25000 (wave per node)

    const float* WgL[4] = {Wg1f, Wg2f, Wg3f, Wg4f};
    const float* bgL[4] = {bg1f, bg2f, bg3f, bg4f};

    // 4 GCN layers; B = X@W, then A = relu(aggregate(B))
    for (int l = 0; l < 4; ++l) {
        if (l == 0)
            gemm_n128<64, 1><<<gemmGrid, 256, 0, stream>>>(x_graph, WgL[0], B, N_NODES, flag);
        else
            gemm_n128<128, 0><<<gemmGrid, 256, 0, stream>>>(A, WgL[l], B, N_NODES, flag);
        gather_agg<<<aggGrid, 256, 0, stream>>>(rowptr, degi, csr_src, csr_w,
                                                B, dinv, bgL[l], A);
    }

    // pooling -> concat[:, 0:256]
    pool_k<<<N_GRAPHS, 128, 0, stream>>>(A, batch, concat);

    // tabular branch -> concat[:, 256:384]
    rowmm<200, true><<<N_GRAPHS, 256, 200 * 4, stream>>>(x_tab, 200, Wt1f, bt1f, t1, 256, flag);
    rowmm<256, false><<<N_GRAPHS, 128, 256 * 4, stream>>>(t1, 256, Wt2f, bt2f, concat + 256, 384, flag);

    // fused head
    rowmm<384, false><<<N_GRAPHS, 256, 384 * 4, stream>>>(concat, 384, Wf1f, bf1f, u1, 256, flag);
    rowmm<256, false><<<N_GRAPHS, 128, 256 * 4, stream>>>(u1, 256, Wf2f, bf2f, u2, 128, flag);
    head3<<<N_GRAPHS / 4, 256, 0, stream>>>(u2, Wf3f, bf3f, d_out, flag);
}

// Round 4
// 863.926 us; speedup vs baseline: 7.7599x; 1.6711x over previous
//
#include <hip/hip_runtime.h>
#include <hip/hip_bf16.h>
#include <math.h>

#define N_NODES  100000
#define N_EDGES  1600000
#define N_GRAPHS 1024

typedef __hip_bfloat16 bf16;
typedef unsigned short u16;
typedef unsigned int   u32;
typedef __attribute__((ext_vector_type(8))) short bf8_t;   // 8 bf16 (4 VGPRs)
typedef __attribute__((ext_vector_type(4))) float f4_t;    // 4 fp32 acc

__device__ __forceinline__ float b2f(bf16 v) { return __bfloat162float(v); }
__device__ __forceinline__ u16 bfbits(float f) {
    bf16 h = __float2bfloat16(f);
    return *reinterpret_cast<u16*>(&h);
}
__device__ __forceinline__ float lo_bf(u32 u) { return __uint_as_float(u << 16); }
__device__ __forceinline__ float hi_bf(u32 u) { return __uint_as_float(u & 0xffff0000u); }

// ---------------- dtype sniff: flag=1 if external float tensors are bf16 ----
__global__ void sniff_dtype(const u16* __restrict__ p, int* __restrict__ flag) {
    if (blockIdx.x == 0 && threadIdx.x == 0) {
        int bad = 0;
        for (int i = 0; i < 256; ++i) {
            float f = __uint_as_float(((u32)p[i]) << 16);
            if (!(fabsf(f) < 100.f)) bad++;
        }
        *flag = (bad == 0) ? 1 : 0;
    }
}

// ---------------- convert external float tensor -> fp32 ws ----------------
__global__ void cvt_f(const void* __restrict__ src, float* __restrict__ dst,
                      int n, const int* __restrict__ flag) {
    int i = blockIdx.x * blockDim.x + threadIdx.x;
    if (i >= n) return;
    if (*flag) dst[i] = b2f(((const bf16*)src)[i]);
    else       dst[i] = ((const float*)src)[i];
}

// ---------------- convert external float tensor -> bf16 ws ----------------
__global__ void cvt_b(const void* __restrict__ src, u16* __restrict__ dst,
                      int n, const int* __restrict__ flag) {
    int i = blockIdx.x * blockDim.x + threadIdx.x;
    if (i >= n) return;
    if (*flag) dst[i] = ((const u16*)src)[i];
    else       dst[i] = bfbits(((const float*)src)[i]);
}

// ---------------- repack fp32 W[K x 128] into MFMA B-frag layout (bf16) ----
// block b = kb*8 + t (kb: k-tile of 32, t: n-tile of 16); within: lane L, j
// element = W[kb*32 + (L>>4)*8 + j][t*16 + (L&15)] -> Wm[b*512 + L*8 + j]
__global__ void repack_w(const float* __restrict__ Wf, u16* __restrict__ Wm, int K) {
    int idx = blockIdx.x * 256 + threadIdx.x;
    if (idx >= K * 128) return;
    int b = idx >> 9, r = idx & 511;
    int L = r >> 3, j = r & 7;
    int kb = b >> 3, t = b & 7;
    int k = kb * 32 + ((L >> 4) << 3) + j;
    int n = (t << 4) + (L & 15);
    Wm[idx] = bfbits(Wf[k * 128 + n]);
}

// ---------------- degree / norm ----------------
__global__ void deg_init(int* degi) {
    int i = blockIdx.x * blockDim.x + threadIdx.x;
    if (i < N_NODES) degi[i] = 2;
}

__global__ void deg_edges(const int* __restrict__ dst, int* __restrict__ degi) {
    int e = blockIdx.x * blockDim.x + threadIdx.x;
    if (e < N_EDGES) atomicAdd(&degi[dst[e]], 1);
}

__global__ void dinv_k(const int* __restrict__ degi, float* __restrict__ dinv) {
    int i = blockIdx.x * blockDim.x + threadIdx.x;
    if (i < N_NODES) dinv[i] = rsqrtf((float)degi[i]);
}

// ---------------- CSR build ----------------
#define SCAN_B 256
__global__ void scan1(const int* __restrict__ degi, int* __restrict__ ex,
                      int* __restrict__ bsum) {
    __shared__ int s[SCAN_B];
    int i = blockIdx.x * SCAN_B + threadIdx.x;
    int v = (i < N_NODES) ? (degi[i] - 2) : 0;
    s[threadIdx.x] = v;
    __syncthreads();
    for (int off = 1; off < SCAN_B; off <<= 1) {
        int t = (threadIdx.x >= off) ? s[threadIdx.x - off] : 0;
        __syncthreads();
        if (threadIdx.x >= off) s[threadIdx.x] += t;
        __syncthreads();
    }
    if (i < N_NODES) ex[i] = s[threadIdx.x] - v;
    if (threadIdx.x == SCAN_B - 1) bsum[blockIdx.x] = s[SCAN_B - 1];
}

__global__ void scan2(int* __restrict__ bsum, int nb) {
    if (blockIdx.x == 0 && threadIdx.x == 0) {
        int acc = 0;
        for (int i = 0; i < nb; ++i) { int t = bsum[i]; bsum[i] = acc; acc += t; }
    }
}

__global__ void scan3(int* __restrict__ rowptr, const int* __restrict__ bsum,
                      int* __restrict__ cnt) {
    int i = blockIdx.x * SCAN_B + threadIdx.x;
    if (i >= N_NODES) return;
    rowptr[i] += bsum[blockIdx.x];
    cnt[i] = 0;
}

__global__ void fill_csr(const int* __restrict__ src, const int* __restrict__ dst,
                         const float* __restrict__ dinv, const int* __restrict__ rowptr,
                         int* __restrict__ cnt, int* __restrict__ csr_src,
                         float* __restrict__ csr_w) {
    int e = blockIdx.x * 256 + threadIdx.x;
    if (e >= N_EDGES) return;
    int s = src[e], d = dst[e];
    int pos = rowptr[d] + atomicAdd(&cnt[d], 1);
    csr_src[pos] = s;
    csr_w[pos] = dinv[s] * dinv[d];
}

// ---------------- MFMA GEMM: Out[M x 128](bf16) = A[M x K](bf16) @ W ----
// block = 4 waves x 16 rows = 64 rows; per wave: 8 n-tiles of 16
template<int K>
__global__ __launch_bounds__(256) void gemm_mfma(const u16* __restrict__ A,
        const u16* __restrict__ Wm, u16* __restrict__ Out, int M)
{
    int wave = threadIdx.x >> 6, lane = threadIdx.x & 63;
    int rowBase = blockIdx.x * 64 + wave * 16;
    int quad = lane >> 4, low = lane & 15;
    int arow = rowBase + low;
    if (arow >= M) arow = M - 1;
    const u16* ap = A + (size_t)arow * K + quad * 8;

    f4_t acc[8];
#pragma unroll
    for (int t = 0; t < 8; ++t) acc[t] = (f4_t)(0.f);

#pragma unroll
    for (int kb = 0; kb < K / 32; ++kb) {
        bf8_t a = *(const bf8_t*)(ap + kb * 32);
#pragma unroll
        for (int t = 0; t < 8; ++t) {
            bf8_t b = *(const bf8_t*)(Wm + (((kb << 3) + t) << 9) + lane * 8);
            acc[t] = __builtin_amdgcn_mfma_f32_16x16x32_bf16(a, b, acc[t], 0, 0, 0);
        }
    }

    int orow0 = rowBase + quad * 4;
#pragma unroll
    for (int t = 0; t < 8; ++t) {
#pragma unroll
        for (int j = 0; j < 4; ++j) {
            int r = orow0 + j;
            if (r < M) Out[(size_t)r * 128 + t * 16 + low] = bfbits(acc[t][j]);
        }
    }
}

// ---------------- fused aggregate (bf16 H): A = relu(bias + 2*dinv^2*H[n] + sum w_e*H[src_e]) ----
// one wave per node, 2 bf16 per lane (uint)
__global__ __launch_bounds__(256) void gather_agg(
        const int* __restrict__ rowptr, const int* __restrict__ degi,
        const int* __restrict__ csr_src, const float* __restrict__ csr_w,
        const u16* __restrict__ H, const float* __restrict__ dinv,
        const float* __restrict__ bias, u16* __restrict__ A)
{
    int node = blockIdx.x * 4 + (threadIdx.x >> 6);
    if (node >= N_NODES) return;
    int lane = threadIdx.x & 63;
    const u32* H2 = (const u32*)H;
    float2 bb = ((const float2*)bias)[lane];
    float dv = dinv[node];
    float selfw = 2.f * dv * dv;
    u32 h0 = H2[(size_t)node * 64 + lane];
    float accx = bb.x + selfw * lo_bf(h0);
    float accy = bb.y + selfw * hi_bf(h0);
    int p = rowptr[node];
    int end = p + (degi[node] - 2);
    for (; p + 4 <= end; p += 4) {
        int s0 = csr_src[p],   s1 = csr_src[p+1];
        int s2 = csr_src[p+2], s3 = csr_src[p+3];
        float w0 = csr_w[p],   w1 = csr_w[p+1];
        float w2 = csr_w[p+2], w3 = csr_w[p+3];
        u32 v0 = H2[(size_t)s0 * 64 + lane];
        u32 v1 = H2[(size_t)s1 * 64 + lane];
        u32 v2 = H2[(size_t)s2 * 64 + lane];
        u32 v3 = H2[(size_t)s3 * 64 + lane];
        accx += w0 * lo_bf(v0) + w1 * lo_bf(v1) + w2 * lo_bf(v2) + w3 * lo_bf(v3);
        accy += w0 * hi_bf(v0) + w1 * hi_bf(v1) + w2 * hi_bf(v2) + w3 * hi_bf(v3);
    }
    for (; p < end; ++p) {
        int s = csr_src[p]; float w = csr_w[p];
        u32 v = H2[(size_t)s * 64 + lane];
        accx += w * lo_bf(v); accy += w * hi_bf(v);
    }
    accx = fmaxf(accx, 0.f);
    accy = fmaxf(accy, 0.f);
    u32 pack = ((u32)bfbits(accy) << 16) | (u32)bfbits(accx);
    ((u32*)A)[(size_t)node * 64 + lane] = pack;
}

// ---------------- per-graph mean/max pooling (batch sorted, bf16 A) ----------------
__global__ __launch_bounds__(128) void pool_k(const u16* __restrict__ A,
        const int* __restrict__ batch, float* __restrict__ concat)
{
    __shared__ int sb[2];
    int g = blockIdx.x;
    if (threadIdx.x == 0) {
        int lo = 0, hi = N_NODES;
        while (lo < hi) { int m = (lo + hi) >> 1; if (batch[m] < g) lo = m + 1; else hi = m; }
        sb[0] = lo;
        hi = N_NODES;
        while (lo < hi) { int m = (lo + hi) >> 1; if (batch[m] < g + 1) lo = m + 1; else hi = m; }
        sb[1] = lo;
    }
    __syncthreads();
    int start = sb[0], end = sb[1];
    int t = threadIdx.x;
    float sum = 0.f, mx = -3.4e38f;
    for (int n = start; n < end; ++n) {
        float v = __uint_as_float(((u32)A[(size_t)n * 128 + t]) << 16);
        sum += v; mx = fmaxf(mx, v);
    }
    int cnt = end - start;
    float mean = sum / (float)(cnt > 0 ? cnt : 1);
    if (cnt == 0) mx = 0.f;
    concat[g * 384 + t] = mean;
    concat[g * 384 + 128 + t] = mx;
}

// ---------------- small row GEMM (fp32 head) ----------------
template<int KD, bool EXT>
__global__ void rowmm(const void* __restrict__ Xv, int ldx,
                      const float* __restrict__ W, const float* __restrict__ bias,
                      float* __restrict__ out, int ldo, const int* __restrict__ flagp)
{
    extern __shared__ float xs[];
    int g = blockIdx.x;
    int col = threadIdx.x;
    int N = blockDim.x;
    const int isb = EXT ? *flagp : 0;
    for (int k = col; k < KD; k += N) {
        size_t off = (size_t)g * ldx + k;
        xs[k] = EXT ? (isb ? b2f(((const bf16*)Xv)[off]) : ((const float*)Xv)[off])
                    : ((const float*)Xv)[off];
    }
    __syncthreads();
    float acc = bias[col];
    for (int k = 0; k < KD; ++k)
        acc += xs[k] * W[(size_t)k * N + col];
    out[(size_t)g * ldo + col] = fmaxf(acc, 0.f);
}

// ---------------- final dot + sigmoid ----------------
__global__ __launch_bounds__(256) void head3(const float* __restrict__ u2,
        const float* __restrict__ Wf3, const float* __restrict__ bf3,
        void* __restrict__ out, const int* __restrict__ flagp)
{
    int g = blockIdx.x * 4 + (threadIdx.x >> 6);
    int lane = threadIdx.x & 63;
    float2 v = ((const float2*)(u2 + (size_t)g * 128))[lane];
    float2 w = ((const float2*)Wf3)[lane];
    float acc = v.x * w.x + v.y * w.y;
    for (int off = 32; off > 0; off >>= 1) acc += __shfl_down(acc, off);
    if (lane == 0) {
        float z = acc + bf3[0];
        float sg = 1.f / (1.f + expf(-z));
        if (*flagp) ((bf16*)out)[g] = __float2bfloat16(sg);
        else        ((float*)out)[g] = sg;
    }
}

extern "C" void kernel_launch(void* const* d_in, const int* in_sizes, int n_in,
                              void* d_out, int out_size, void* d_ws, size_t ws_size,
                              hipStream_t stream) {
    const void* x_graph    = d_in[0];
    const int*  edge_index = (const int*)d_in[1];
    const int*  batch      = (const int*)d_in[2];
    const void* x_tab      = d_in[3];

    const int* src  = edge_index;
    const int* dstp = edge_index + N_EDGES;

    // ---------------- workspace layout ----------------
    char* wsp = (char*)d_ws;
    int*  flag = (int*)wsp;                      wsp += 16;
    u16*  A16  = (u16*)wsp;                      wsp += (size_t)N_NODES * 128 * 2;
    u16*  B16  = (u16*)wsp;                      wsp += (size_t)N_NODES * 128 * 2;
    u16*  X16  = (u16*)wsp;                      wsp += (size_t)N_NODES * 64 * 2;
    u16*  Wm[4];
    Wm[0] = (u16*)wsp;                           wsp += 64 * 128 * 2;
    Wm[1] = (u16*)wsp;                           wsp += 128 * 128 * 2;
    Wm[2] = (u16*)wsp;                           wsp += 128 * 128 * 2;
    Wm[3] = (u16*)wsp;                           wsp += 128 * 128 * 2;
    float* p = (float*)wsp;
    float* Wg1f = p; p += 64 * 128;  float* bg1f = p; p += 128;
    float* Wg2f = p; p += 128 * 128; float* bg2f = p; p += 128;
    float* Wg3f = p; p += 128 * 128; float* bg3f = p; p += 128;
    float* Wg4f = p; p += 128 * 128; float* bg4f = p; p += 128;
    float* Wt1f = p; p += 200 * 256; float* bt1f = p; p += 256;
    float* Wt2f = p; p += 256 * 128; float* bt2f = p; p += 128;
    float* Wf1f = p; p += 384 * 256; float* bf1f = p; p += 256;
    float* Wf2f = p; p += 256 * 128; float* bf2f = p; p += 128;
    float* Wf3f = p; p += 128;       float* bf3f = p; p += 4;
    int*   degi   = (int*)p;            p += N_NODES;
    float* dinv   = p;                  p += N_NODES;
    int*   rowptr = (int*)p;            p += N_NODES;
    int*   cnt    = (int*)p;            p += N_NODES;
    int*   bsum   = (int*)p;            p += 512;
    int*   csr_src= (int*)p;            p += N_EDGES;
    float* csr_w  = p;                  p += N_EDGES;
    float* concat = p;                  p += N_GRAPHS * 384;
    float* t1     = p;                  p += N_GRAPHS * 256;
    float* u1     = p;                  p += N_GRAPHS * 256;
    float* u2     = p;                  p += N_GRAPHS * 128;

    // ---------------- dtype sniff + weight conversion ----------------
    sniff_dtype<<<1, 64, 0, stream>>>((const u16*)x_graph, flag);
    const float* Wfp[9] = {Wg1f, Wg2f, Wg3f, Wg4f, Wt1f, Wt2f, Wf1f, Wf2f, Wf3f};
    const float* bfp[9] = {bg1f, bg2f, bg3f, bg4f, bt1f, bt2f, bf1f, bf2f, bf3f};
    const int    wsz[9] = {64*128, 128*128, 128*128, 128*128, 200*256, 256*128,
                           384*256, 256*128, 128};
    const int    bsz[9] = {128, 128, 128, 128, 256, 128, 256, 128, 1};
    for (int i = 0; i < 9; ++i) {
        cvt_f<<<(wsz[i] + 255) / 256, 256, 0, stream>>>(d_in[4 + 2*i], (float*)Wfp[i], wsz[i], flag);
        cvt_f<<<(bsz[i] + 255) / 256, 256, 0, stream>>>(d_in[5 + 2*i], (float*)bfp[i], bsz[i], flag);
    }
    // GCN weights -> MFMA bf16 layout; x_graph -> bf16
    repack_w<<<(64 * 128 + 255) / 256, 256, 0, stream>>>(Wg1f, Wm[0], 64);
    repack_w<<<(128 * 128 + 255) / 256, 256, 0, stream>>>(Wg2f, Wm[1], 128);
    repack_w<<<(128 * 128 + 255) / 256, 256, 0, stream>>>(Wg3f, Wm[2], 128);
    repack_w<<<(128 * 128 + 255) / 256, 256, 0, stream>>>(Wg4f, Wm[3], 128);
    cvt_b<<<(N_NODES * 64 + 255) / 256, 256, 0, stream>>>(x_graph, X16, N_NODES * 64, flag);

    // ---------------- degree / norm / CSR ----------------
    const int nb = (N_NODES + SCAN_B - 1) / SCAN_B;
    deg_init<<<(N_NODES + 255) / 256, 256, 0, stream>>>(degi);
    deg_edges<<<(N_EDGES + 255) / 256, 256, 0, stream>>>(dstp, degi);
    dinv_k<<<(N_NODES + 255) / 256, 256, 0, stream>>>(degi, dinv);
    scan1<<<nb, SCAN_B, 0, stream>>>(degi, rowptr, bsum);
    scan2<<<1, 64, 0, stream>>>(bsum, nb);
    scan3<<<nb, SCAN_B, 0, stream>>>(rowptr, bsum, cnt);
    fill_csr<<<(N_EDGES + 255) / 256, 256, 0, stream>>>(src, dstp, dinv, rowptr, cnt,
                                                        csr_src, csr_w);

    const int gemmGrid = (N_NODES + 63) / 64;   // 1563
    const int aggGrid  = (N_NODES + 3) / 4;     // 25000

    const float* bgL[4] = {bg1f, bg2f, bg3f, bg4f};

    // 4 GCN layers; B16 = X@W (MFMA), then A16 = relu(aggregate(B16))
    for (int l = 0; l < 4; ++l) {
        if (l == 0)
            gemm_mfma<64><<<gemmGrid, 256, 0, stream>>>(X16, Wm[0], B16, N_NODES);
        else
            gemm_mfma<128><<<gemmGrid, 256, 0, stream>>>(A16, Wm[l], B16, N_NODES);
        gather_agg<<<aggGrid, 256, 0, stream>>>(rowptr, degi, csr_src, csr_w,
                                                B16, dinv, bgL[l], A16);
    }

    // pooling -> concat[:, 0:256]
    pool_k<<<N_GRAPHS, 128, 0, stream>>>(A16, batch, concat);

    // tabular branch -> concat[:, 256:384]
    rowmm<200, true><<<N_GRAPHS, 256, 200 * 4, stream>>>(x_tab, 200, Wt1f, bt1f, t1, 256, flag);
    rowmm<256, false><<<N_GRAPHS, 128, 256 * 4, stream>>>(t1, 256, Wt2f, bt2f, concat + 256, 384, flag);

    // fused head
    rowmm<384, false><<<N_GRAPHS, 256, 384 * 4, stream>>>(concat, 384, Wf1f, bf1f, u1, 256, flag);
    rowmm<256, false><<<N_GRAPHS, 128, 256 * 4, stream>>>(u1, 256, Wf2f, bf2f, u2, 128, flag);
    head3<<<N_GRAPHS / 4, 256, 0, stream>>>(u2, Wf3f, bf3f, d_out, flag);
}

// Round 5
// 772.660 us; speedup vs baseline: 8.6765x; 1.1181x over previous
//
#include <hip/hip_runtime.h>
#include <hip/hip_bf16.h>
#include <math.h>

#define N_NODES  100000
#define N_EDGES  1600000
#define N_GRAPHS 1024

typedef __hip_bfloat16 bf16;
typedef unsigned short u16;
typedef unsigned int   u32;
typedef __attribute__((ext_vector_type(8))) short bf8_t;   // 8 bf16 (4 VGPRs)
typedef __attribute__((ext_vector_type(4))) float f4_t;    // 4 fp32 acc

__device__ __forceinline__ float b2f(bf16 v) { return __bfloat162float(v); }
__device__ __forceinline__ u16 bfbits(float f) {
    bf16 h = __float2bfloat16(f);
    return *reinterpret_cast<u16*>(&h);
}
__device__ __forceinline__ float lo_bf(u32 u) { return __uint_as_float(u << 16); }
__device__ __forceinline__ float hi_bf(u32 u) { return __uint_as_float(u & 0xffff0000u); }

// ---------------- dtype sniff: flag=1 if external float tensors are bf16 ----
__global__ void sniff_dtype(const u16* __restrict__ p, int* __restrict__ flag) {
    if (blockIdx.x == 0 && threadIdx.x == 0) {
        int bad = 0;
        for (int i = 0; i < 256; ++i) {
            float f = __uint_as_float(((u32)p[i]) << 16);
            if (!(fabsf(f) < 100.f)) bad++;
        }
        *flag = (bad == 0) ? 1 : 0;
    }
}

// ---------------- fused weight prep: cvt->fp32 or repack->MFMA bf16 -------
#define NT 18
struct WTask { const void* src; void* dst; int n; int mode; int K; };
struct PrepArgs { WTask t[NT]; int bstart[NT]; };

__global__ void prep_k(PrepArgs args, const int* __restrict__ flag) {
    int b = blockIdx.x, ti = 0;
    while (ti < NT - 1 && b >= args.bstart[ti + 1]) ++ti;
    int idx = (b - args.bstart[ti]) * 256 + threadIdx.x;
    WTask tk = args.t[ti];
    if (idx >= tk.n) return;
    int isb = *flag;
    if (tk.mode == 0) {
        float v = isb ? b2f(((const bf16*)tk.src)[idx]) : ((const float*)tk.src)[idx];
        ((float*)tk.dst)[idx] = v;
    } else {
        // MFMA B-frag layout: element = W[kb*32+(L>>4)*8+j][t*16+(L&15)]
        int bseg = idx >> 9, r = idx & 511;
        int L = r >> 3, j = r & 7;
        int kb = bseg >> 3, tt = bseg & 7;
        int k = kb * 32 + ((L >> 4) << 3) + j;
        int n = (tt << 4) + (L & 15);
        int so = k * 128 + n;
        float v = isb ? b2f(((const bf16*)tk.src)[so]) : ((const float*)tk.src)[so];
        ((u16*)tk.dst)[idx] = bfbits(v);
    }
}

// ---------------- convert external float tensor -> bf16 ws ----------------
__global__ void cvt_b(const void* __restrict__ src, u16* __restrict__ dst,
                      int n, const int* __restrict__ flag) {
    int i = blockIdx.x * blockDim.x + threadIdx.x;
    if (i >= n) return;
    if (*flag) dst[i] = ((const u16*)src)[i];
    else       dst[i] = bfbits(((const float*)src)[i]);
}

// ---------------- degree / norm ----------------
__global__ void deg_init(int* degi) {
    int i = blockIdx.x * blockDim.x + threadIdx.x;
    if (i < N_NODES) degi[i] = 2;
}

__global__ void deg_edges(const int* __restrict__ dst, int* __restrict__ degi) {
    int e = blockIdx.x * blockDim.x + threadIdx.x;
    if (e < N_EDGES) atomicAdd(&degi[dst[e]], 1);
}

__global__ void dinv_k(const int* __restrict__ degi, float* __restrict__ dinv) {
    int i = blockIdx.x * blockDim.x + threadIdx.x;
    if (i < N_NODES) dinv[i] = rsqrtf((float)degi[i]);
}

// ---------------- CSR build ----------------
#define SCAN_B 256
__global__ void scan1(const int* __restrict__ degi, int* __restrict__ ex,
                      int* __restrict__ bsum) {
    __shared__ int s[SCAN_B];
    int i = blockIdx.x * SCAN_B + threadIdx.x;
    int v = (i < N_NODES) ? (degi[i] - 2) : 0;
    s[threadIdx.x] = v;
    __syncthreads();
    for (int off = 1; off < SCAN_B; off <<= 1) {
        int t = (threadIdx.x >= off) ? s[threadIdx.x - off] : 0;
        __syncthreads();
        if (threadIdx.x >= off) s[threadIdx.x] += t;
        __syncthreads();
    }
    if (i < N_NODES) ex[i] = s[threadIdx.x] - v;
    if (threadIdx.x == SCAN_B - 1) bsum[blockIdx.x] = s[SCAN_B - 1];
}

// one-block LDS scan of block sums (nb <= 512)
__global__ void scan2(int* __restrict__ bsum, int nb) {
    __shared__ int s[512];
    int i = threadIdx.x;
    int v = (i < nb) ? bsum[i] : 0;
    s[i] = v;
    __syncthreads();
    for (int off = 1; off < 512; off <<= 1) {
        int t = (i >= off) ? s[i - off] : 0;
        __syncthreads();
        if (i >= off) s[i] += t;
        __syncthreads();
    }
    if (i < nb) bsum[i] = s[i] - v;   // exclusive
}

__global__ void scan3(int* __restrict__ rowptr, const int* __restrict__ bsum,
                      int* __restrict__ cnt) {
    int i = blockIdx.x * SCAN_B + threadIdx.x;
    if (i >= N_NODES) return;
    rowptr[i] += bsum[blockIdx.x];
    cnt[i] = 0;
}

// packed CSR entry: int2{src, weight_bits} — single 8B scatter per edge
__global__ void fill_csr(const int* __restrict__ src, const int* __restrict__ dst,
                         const float* __restrict__ dinv, const int* __restrict__ rowptr,
                         int* __restrict__ cnt, int2* __restrict__ csrp) {
    int e = blockIdx.x * 256 + threadIdx.x;
    if (e >= N_EDGES) return;
    int s = src[e], d = dst[e];
    int pos = rowptr[d] + atomicAdd(&cnt[d], 1);
    csrp[pos] = make_int2(s, __float_as_int(dinv[s] * dinv[d]));
}

// ---------------- MFMA GEMM: Out[M x 128](bf16) = A[M x K](bf16) @ W ----
// block = 4 waves x 16 rows = 64 rows; per wave: 8 n-tiles of 16
// EPI: fuse +bias and relu into epilogue (layer-1 (AX)W order)
template<int K, bool EPI>
__global__ __launch_bounds__(256) void gemm_mfma(const u16* __restrict__ A,
        const u16* __restrict__ Wm, const float* __restrict__ bias,
        u16* __restrict__ Out, int M)
{
    int wave = threadIdx.x >> 6, lane = threadIdx.x & 63;
    int rowBase = blockIdx.x * 64 + wave * 16;
    int quad = lane >> 4, low = lane & 15;
    int arow = rowBase + low;
    if (arow >= M) arow = M - 1;
    const u16* ap = A + (size_t)arow * K + quad * 8;

    f4_t acc[8];
#pragma unroll
    for (int t = 0; t < 8; ++t) acc[t] = (f4_t)(0.f);

#pragma unroll
    for (int kb = 0; kb < K / 32; ++kb) {
        bf8_t a = *(const bf8_t*)(ap + kb * 32);
#pragma unroll
        for (int t = 0; t < 8; ++t) {
            bf8_t b = *(const bf8_t*)(Wm + (((kb << 3) + t) << 9) + lane * 8);
            acc[t] = __builtin_amdgcn_mfma_f32_16x16x32_bf16(a, b, acc[t], 0, 0, 0);
        }
    }

    int orow0 = rowBase + quad * 4;
#pragma unroll
    for (int t = 0; t < 8; ++t) {
        float bn = EPI ? bias[t * 16 + low] : 0.f;
#pragma unroll
        for (int j = 0; j < 4; ++j) {
            int r = orow0 + j;
            float v = acc[t][j];
            if (EPI) v = fmaxf(v + bn, 0.f);
            if (r < M) Out[(size_t)r * 128 + t * 16 + low] = bfbits(v);
        }
    }
}

// ---------------- layer-1 gather on 64-wide X: G = A_hat X ----------------
// one wave per node; half-wave per edge (2 edges in flight), shfl-combine
__global__ __launch_bounds__(256) void gather_x(
        const int* __restrict__ rowptr, const int* __restrict__ cnt,
        const int2* __restrict__ csrp, const u16* __restrict__ X,
        const float* __restrict__ dinv, u16* __restrict__ G)
{
    int node = blockIdx.x * 4 + (threadIdx.x >> 6);
    if (node >= N_NODES) return;
    int lane = threadIdx.x & 63;
    int half = lane >> 5, fi = lane & 31;
    const u32* X2 = (const u32*)X;   // 32 u32 per row (64 bf16)
    float accx = 0.f, accy = 0.f;
    if (half == 0) {
        float dv = dinv[node];
        float s = 2.f * dv * dv;
        u32 h0 = X2[(size_t)node * 32 + fi];
        accx = s * lo_bf(h0); accy = s * hi_bf(h0);
    }
    int rp = rowptr[node];
    int end = rp + cnt[node];
    int p = rp + half;
    for (; p + 8 <= end; p += 8) {
        int2 m0 = csrp[p],     m1 = csrp[p + 2];
        int2 m2 = csrp[p + 4], m3 = csrp[p + 6];
        u32 v0 = X2[(size_t)m0.x * 32 + fi];
        u32 v1 = X2[(size_t)m1.x * 32 + fi];
        u32 v2 = X2[(size_t)m2.x * 32 + fi];
        u32 v3 = X2[(size_t)m3.x * 32 + fi];
        float w0 = __int_as_float(m0.y), w1 = __int_as_float(m1.y);
        float w2 = __int_as_float(m2.y), w3 = __int_as_float(m3.y);
        accx += w0 * lo_bf(v0) + w1 * lo_bf(v1) + w2 * lo_bf(v2) + w3 * lo_bf(v3);
        accy += w0 * hi_bf(v0) + w1 * hi_bf(v1) + w2 * hi_bf(v2) + w3 * hi_bf(v3);
    }
    for (; p < end; p += 2) {
        int2 m = csrp[p];
        u32 v = X2[(size_t)m.x * 32 + fi];
        float w = __int_as_float(m.y);
        accx += w * lo_bf(v); accy += w * hi_bf(v);
    }
    accx += __shfl_xor(accx, 32);
    accy += __shfl_xor(accy, 32);
    if (half == 0) {
        u32 pack = ((u32)bfbits(accy) << 16) | (u32)bfbits(accx);
        ((u32*)G)[(size_t)node * 32 + fi] = pack;
    }
}

// ---------------- fused aggregate (128-wide): A = relu(b + 2dinv^2 H[n] + sum w_e H[src]) ----
__global__ __launch_bounds__(256) void gather_agg(
        const int* __restrict__ rowptr, const int* __restrict__ cnt,
        const int2* __restrict__ csrp, const u16* __restrict__ H,
        const float* __restrict__ dinv, const float* __restrict__ bias,
        u16* __restrict__ A)
{
    int node = blockIdx.x * 4 + (threadIdx.x >> 6);
    if (node >= N_NODES) return;
    int lane = threadIdx.x & 63;
    const u32* H2 = (const u32*)H;   // 64 u32 per row (128 bf16)
    float2 bb = ((const float2*)bias)[lane];
    float dv = dinv[node];
    float selfw = 2.f * dv * dv;
    u32 h0 = H2[(size_t)node * 64 + lane];
    float accx = bb.x + selfw * lo_bf(h0);
    float accy = bb.y + selfw * hi_bf(h0);
    int p = rowptr[node];
    int end = p + cnt[node];
    for (; p + 8 <= end; p += 8) {
        int2 m0 = csrp[p],     m1 = csrp[p + 1];
        int2 m2 = csrp[p + 2], m3 = csrp[p + 3];
        int2 m4 = csrp[p + 4], m5 = csrp[p + 5];
        int2 m6 = csrp[p + 6], m7 = csrp[p + 7];
        u32 v0 = H2[(size_t)m0.x * 64 + lane];
        u32 v1 = H2[(size_t)m1.x * 64 + lane];
        u32 v2 = H2[(size_t)m2.x * 64 + lane];
        u32 v3 = H2[(size_t)m3.x * 64 + lane];
        u32 v4 = H2[(size_t)m4.x * 64 + lane];
        u32 v5 = H2[(size_t)m5.x * 64 + lane];
        u32 v6 = H2[(size_t)m6.x * 64 + lane];
        u32 v7 = H2[(size_t)m7.x * 64 + lane];
        float w0 = __int_as_float(m0.y), w1 = __int_as_float(m1.y);
        float w2 = __int_as_float(m2.y), w3 = __int_as_float(m3.y);
        float w4 = __int_as_float(m4.y), w5 = __int_as_float(m5.y);
        float w6 = __int_as_float(m6.y), w7 = __int_as_float(m7.y);
        accx += w0 * lo_bf(v0) + w1 * lo_bf(v1) + w2 * lo_bf(v2) + w3 * lo_bf(v3)
              + w4 * lo_bf(v4) + w5 * lo_bf(v5) + w6 * lo_bf(v6) + w7 * lo_bf(v7);
        accy += w0 * hi_bf(v0) + w1 * hi_bf(v1) + w2 * hi_bf(v2) + w3 * hi_bf(v3)
              + w4 * hi_bf(v4) + w5 * hi_bf(v5) + w6 * hi_bf(v6) + w7 * hi_bf(v7);
    }
    for (; p < end; ++p) {
        int2 m = csrp[p];
        u32 v = H2[(size_t)m.x * 64 + lane];
        float w = __int_as_float(m.y);
        accx += w * lo_bf(v); accy += w * hi_bf(v);
    }
    accx = fmaxf(accx, 0.f);
    accy = fmaxf(accy, 0.f);
    u32 pack = ((u32)bfbits(accy) << 16) | (u32)bfbits(accx);
    ((u32*)A)[(size_t)node * 64 + lane] = pack;
}

// ---------------- per-graph mean/max pooling (batch sorted, bf16 A) --------
__global__ __launch_bounds__(128) void pool_k(const u16* __restrict__ A,
        const int* __restrict__ batch, float* __restrict__ concat)
{
    __shared__ int sb[2];
    int g = blockIdx.x;
    if (threadIdx.x == 0) {
        int lo = 0, hi = N_NODES;
        while (lo < hi) { int m = (lo + hi) >> 1; if (batch[m] < g) lo = m + 1; else hi = m; }
        sb[0] = lo;
        hi = N_NODES;
        while (lo < hi) { int m = (lo + hi) >> 1; if (batch[m] < g + 1) lo = m + 1; else hi = m; }
        sb[1] = lo;
    }
    __syncthreads();
    int start = sb[0], end = sb[1];
    int t = threadIdx.x;
    float sum = 0.f, mx = -3.4e38f;
    for (int n = start; n < end; ++n) {
        float v = __uint_as_float(((u32)A[(size_t)n * 128 + t]) << 16);
        sum += v; mx = fmaxf(mx, v);
    }
    int cnt = end - start;
    float mean = sum / (float)(cnt > 0 ? cnt : 1);
    if (cnt == 0) mx = 0.f;
    concat[g * 384 + t] = mean;
    concat[g * 384 + 128 + t] = mx;
}

// ---------------- small row GEMM (fp32 head) ----------------
template<int KD, bool EXT>
__global__ void rowmm(const void* __restrict__ Xv, int ldx,
                      const float* __restrict__ W, const float* __restrict__ bias,
                      float* __restrict__ out, int ldo, const int* __restrict__ flagp)
{
    extern __shared__ float xs[];
    int g = blockIdx.x;
    int col = threadIdx.x;
    int N = blockDim.x;
    const int isb = EXT ? *flagp : 0;
    for (int k = col; k < KD; k += N) {
        size_t off = (size_t)g * ldx + k;
        xs[k] = EXT ? (isb ? b2f(((const bf16*)Xv)[off]) : ((const float*)Xv)[off])
                    : ((const float*)Xv)[off];
    }
    __syncthreads();
    float acc = bias[col];
    for (int k = 0; k < KD; ++k)
        acc += xs[k] * W[(size_t)k * N + col];
    out[(size_t)g * ldo + col] = fmaxf(acc, 0.f);
}

// ---------------- final dot + sigmoid ----------------
__global__ __launch_bounds__(256) void head3(const float* __restrict__ u2,
        const float* __restrict__ Wf3, const float* __restrict__ bf3,
        void* __restrict__ out, const int* __restrict__ flagp)
{
    int g = blockIdx.x * 4 + (threadIdx.x >> 6);
    int lane = threadIdx.x & 63;
    float2 v = ((const float2*)(u2 + (size_t)g * 128))[lane];
    float2 w = ((const float2*)Wf3)[lane];
    float acc = v.x * w.x + v.y * w.y;
    for (int off = 32; off > 0; off >>= 1) acc += __shfl_down(acc, off);
    if (lane == 0) {
        float z = acc + bf3[0];
        float sg = 1.f / (1.f + expf(-z));
        if (*flagp) ((bf16*)out)[g] = __float2bfloat16(sg);
        else        ((float*)out)[g] = sg;
    }
}

extern "C" void kernel_launch(void* const* d_in, const int* in_sizes, int n_in,
                              void* d_out, int out_size, void* d_ws, size_t ws_size,
                              hipStream_t stream) {
    const void* x_graph    = d_in[0];
    const int*  edge_index = (const int*)d_in[1];
    const int*  batch      = (const int*)d_in[2];
    const void* x_tab      = d_in[3];

    const int* src  = edge_index;
    const int* dstp = edge_index + N_EDGES;

    // ---------------- workspace layout ----------------
    char* wsp = (char*)d_ws;
    int*  flag = (int*)wsp;                      wsp += 16;
    u16*  A16  = (u16*)wsp;                      wsp += (size_t)N_NODES * 128 * 2;
    u16*  B16  = (u16*)wsp;                      wsp += (size_t)N_NODES * 128 * 2;
    u16*  X16  = (u16*)wsp;                      wsp += (size_t)N_NODES * 64 * 2;
    u16*  G16  = (u16*)wsp;                      wsp += (size_t)N_NODES * 64 * 2;
    u16*  Wm[4];
    Wm[0] = (u16*)wsp;                           wsp += 64 * 128 * 2;
    Wm[1] = (u16*)wsp;                           wsp += 128 * 128 * 2;
    Wm[2] = (u16*)wsp;                           wsp += 128 * 128 * 2;
    Wm[3] = (u16*)wsp;                           wsp += 128 * 128 * 2;
    float* p = (float*)wsp;
    float* bg1f = p; p += 128;
    float* bg2f = p; p += 128;
    float* bg3f = p; p += 128;
    float* bg4f = p; p += 128;
    float* Wt1f = p; p += 200 * 256; float* bt1f = p; p += 256;
    float* Wt2f = p; p += 256 * 128; float* bt2f = p; p += 128;
    float* Wf1f = p; p += 384 * 256; float* bf1f = p; p += 256;
    float* Wf2f = p; p += 256 * 128; float* bf2f = p; p += 128;
    float* Wf3f = p; p += 128;       float* bf3f = p; p += 4;
    int*   degi   = (int*)p;            p += N_NODES;
    float* dinv   = p;                  p += N_NODES;
    int*   rowptr = (int*)p;            p += N_NODES;
    int*   cnt    = (int*)p;            p += N_NODES;
    int*   bsum   = (int*)p;            p += 512;
    int2*  csrp   = (int2*)p;           p += 2 * N_EDGES;
    float* concat = p;                  p += N_GRAPHS * 384;
    float* t1     = p;                  p += N_GRAPHS * 256;
    float* u1     = p;                  p += N_GRAPHS * 256;
    float* u2     = p;                  p += N_GRAPHS * 128;

    // ---------------- dtype sniff + fused weight prep ----------------
    sniff_dtype<<<1, 64, 0, stream>>>((const u16*)x_graph, flag);

    PrepArgs pa;
    auto setT = [&](int i, const void* s, void* d, int n, int mode, int K) {
        pa.t[i].src = s; pa.t[i].dst = d; pa.t[i].n = n; pa.t[i].mode = mode; pa.t[i].K = K;
    };
    setT(0,  d_in[4],  Wm[0], 64 * 128, 1, 64);
    setT(1,  d_in[6],  Wm[1], 128 * 128, 1, 128);
    setT(2,  d_in[8],  Wm[2], 128 * 128, 1, 128);
    setT(3,  d_in[10], Wm[3], 128 * 128, 1, 128);
    setT(4,  d_in[12], Wt1f, 200 * 256, 0, 0);
    setT(5,  d_in[14], Wt2f, 256 * 128, 0, 0);
    setT(6,  d_in[16], Wf1f, 384 * 256, 0, 0);
    setT(7,  d_in[18], Wf2f, 256 * 128, 0, 0);
    setT(8,  d_in[20], Wf3f, 128, 0, 0);
    setT(9,  d_in[5],  bg1f, 128, 0, 0);
    setT(10, d_in[7],  bg2f, 128, 0, 0);
    setT(11, d_in[9],  bg3f, 128, 0, 0);
    setT(12, d_in[11], bg4f, 128, 0, 0);
    setT(13, d_in[13], bt1f, 256, 0, 0);
    setT(14, d_in[15], bt2f, 128, 0, 0);
    setT(15, d_in[17], bf1f, 256, 0, 0);
    setT(16, d_in[19], bf2f, 128, 0, 0);
    setT(17, d_in[21], bf3f, 1, 0, 0);
    int totalBlocks = 0;
    for (int i = 0; i < NT; ++i) {
        pa.bstart[i] = totalBlocks;
        totalBlocks += (pa.t[i].n + 255) / 256;
    }
    prep_k<<<totalBlocks, 256, 0, stream>>>(pa, flag);
    cvt_b<<<(N_NODES * 64 + 255) / 256, 256, 0, stream>>>(x_graph, X16, N_NODES * 64, flag);

    // ---------------- degree / norm / CSR ----------------
    const int nb = (N_NODES + SCAN_B - 1) / SCAN_B;   // 391
    deg_init<<<(N_NODES + 255) / 256, 256, 0, stream>>>(degi);
    deg_edges<<<(N_EDGES + 255) / 256, 256, 0, stream>>>(dstp, degi);
    dinv_k<<<(N_NODES + 255) / 256, 256, 0, stream>>>(degi, dinv);
    scan1<<<nb, SCAN_B, 0, stream>>>(degi, rowptr, bsum);
    scan2<<<1, 512, 0, stream>>>(bsum, nb);
    scan3<<<nb, SCAN_B, 0, stream>>>(rowptr, bsum, cnt);
    fill_csr<<<(N_EDGES + 255) / 256, 256, 0, stream>>>(src, dstp, dinv, rowptr, cnt, csrp);

    const int gemmGrid = (N_NODES + 63) / 64;   // 1563
    const int aggGrid  = (N_NODES + 3) / 4;     // 25000

    // ---- layer 1 (reassociated): G = A_hat X ; A = relu(G W1 + b1) ----
    gather_x<<<aggGrid, 256, 0, stream>>>(rowptr, cnt, csrp, X16, dinv, G16);
    gemm_mfma<64, true><<<gemmGrid, 256, 0, stream>>>(G16, Wm[0], bg1f, A16, N_NODES);

    // ---- layers 2-4: B = A W_l ; A = relu(agg(B) + b_l) ----
    const float* bgL[4] = {bg1f, bg2f, bg3f, bg4f};
    for (int l = 1; l < 4; ++l) {
        gemm_mfma<128, false><<<gemmGrid, 256, 0, stream>>>(A16, Wm[l], nullptr, B16, N_NODES);
        gather_agg<<<aggGrid, 256, 0, stream>>>(rowptr, cnt, csrp, B16, dinv, bgL[l], A16);
    }

    // pooling -> concat[:, 0:256]
    pool_k<<<N_GRAPHS, 128, 0, stream>>>(A16, batch, concat);

    // tabular branch -> concat[:, 256:384]
    rowmm<200, true><<<N_GRAPHS, 256, 200 * 4, stream>>>(x_tab, 200, Wt1f, bt1f, t1, 256, flag);
    rowmm<256, false><<<N_GRAPHS, 128, 256 * 4, stream>>>(t1, 256, Wt2f, bt2f, concat + 256, 384, flag);

    // fused head
    rowmm<384, false><<<N_GRAPHS, 256, 384 * 4, stream>>>(concat, 384, Wf1f, bf1f, u1, 256, flag);
    rowmm<256, false><<<N_GRAPHS, 128, 256 * 4, stream>>>(u1, 256, Wf2f, bf2f, u2, 128, flag);
    head3<<<N_GRAPHS / 4, 256, 0, stream>>>(u2, Wf3f, bf3f, d_out, flag);
}